// Round 1
// baseline (79.011 us; speedup 1.0000x reference)
//
#include <hip/hip_runtime.h>

constexpr int STRU = 68;   // row stride in u32 (272 B; rows 16B-aligned)

typedef short v8s __attribute__((ext_vector_type(8)));
typedef float v4f __attribute__((ext_vector_type(4)));

// fp32 -> packed (bf16_hi << 16) | bf16_lo. hi = truncated, lo = Dekker remainder
// rounded half-up. Reconstruction error ~2^-17 relative.
__device__ __forceinline__ unsigned packhl(float x) {
    unsigned xb = __builtin_bit_cast(unsigned, x);
    unsigned hb = xb & 0xffff0000u;
    float lof = x - __builtin_bit_cast(float, hb);           // exact
    unsigned lb = __builtin_bit_cast(unsigned, lof) + 0x8000u;
    return __builtin_amdgcn_perm(xb, lb, 0x07060302u);       // [hi16(xb) | hi16(lb)]
}

__device__ __forceinline__ float unpackf(unsigned v) {
    float h = __builtin_bit_cast(float, v & 0xffff0000u);
    float l = __builtin_bit_cast(float, v << 16);
    return h + l;
}

// load 8 packed u32 (one MFMA k-fragment of a row) -> hi/lo bf16x8
__device__ __forceinline__ void load_frag(const unsigned* p, v8s& hi, v8s& lo) {
    uint4 a = *(const uint4*)p;
    uint4 b = *(const uint4*)(p + 4);
    uint4 hw, lw;
    hw.x = __builtin_amdgcn_perm(a.y, a.x, 0x07060302u);
    hw.y = __builtin_amdgcn_perm(a.w, a.z, 0x07060302u);
    hw.z = __builtin_amdgcn_perm(b.y, b.x, 0x07060302u);
    hw.w = __builtin_amdgcn_perm(b.w, b.z, 0x07060302u);
    lw.x = __builtin_amdgcn_perm(a.y, a.x, 0x05040100u);
    lw.y = __builtin_amdgcn_perm(a.w, a.z, 0x05040100u);
    lw.z = __builtin_amdgcn_perm(b.y, b.x, 0x05040100u);
    lw.w = __builtin_amdgcn_perm(b.w, b.z, 0x05040100u);
    hi = __builtin_bit_cast(v8s, hw);
    lo = __builtin_bit_cast(v8s, lw);
}

#define MFMA __builtin_amdgcn_mfma_f32_16x16x32_bf16

// D = P * Q^T (64x64, packed LDS operands), 16 waves, 1 tile/wave (4x4 grid).
// MODE 0: packed->D. 1: +I, packed->D. 2: fp32->G (global, row stride 64).
// MODE 3: packed->D AND transposed packed->DT (b128 per tile).
// MODE 4: ca*v -> D; ca*v + I -> DT  (both normal orientation).
// MODE 5: t=unpack(R[row][col]); ca*t - I + cb*v -> D; ca*t - I - cb*v -> DT.
template<int MODE>
__device__ __forceinline__ void mm64(const unsigned* __restrict__ P,
                                     const unsigned* __restrict__ Q,
                                     unsigned* D, unsigned* DT, float* G,
                                     const unsigned* R, float ca, float cb,
                                     int tid) {
    const int lane = tid & 63, w = tid >> 6;   // w in [0,16)
    const int nh = lane & 15, qh = lane >> 4;
    const int tr = w >> 2, tc = w & 3;         // wave owns tile (tr, tc)
    v4f acc = {0, 0, 0, 0};
    #pragma unroll
    for (int kk = 0; kk < 2; ++kk) {
        const int kc = kk * 32 + qh * 8;
        v8s ph, pl, bh, bl;
        load_frag(P + (tr * 16 + nh) * STRU + kc, ph, pl);
        load_frag(Q + (tc * 16 + nh) * STRU + kc, bh, bl);
        acc = MFMA(ph, bh, acc, 0, 0, 0);
        acc = MFMA(ph, bl, acc, 0, 0, 0);
        acc = MFMA(pl, bh, acc, 0, 0, 0);
    }
    const int row0 = tr * 16 + qh * 4;
    const int col  = tc * 16 + nh;
    if constexpr (MODE == 2) {
        #pragma unroll
        for (int e = 0; e < 4; ++e) G[(row0 + e) * 64 + col] = acc[e];
    } else if constexpr (MODE == 0) {
        #pragma unroll
        for (int e = 0; e < 4; ++e)
            D[(row0 + e) * STRU + col] = packhl(acc[e]);
    } else if constexpr (MODE == 1) {
        #pragma unroll
        for (int e = 0; e < 4; ++e) {
            float v = acc[e] + ((row0 + e) == col ? 1.0f : 0.0f);
            D[(row0 + e) * STRU + col] = packhl(v);
        }
    } else if constexpr (MODE == 3) {
        uint4 tp;
        #pragma unroll
        for (int e = 0; e < 4; ++e) {
            unsigned pk = packhl(acc[e]);
            D[(row0 + e) * STRU + col] = pk;
            ((unsigned*)&tp)[e] = pk;
        }
        *(uint4*)&DT[col * STRU + row0] = tp;   // DT[col][row0..row0+3]
    } else if constexpr (MODE == 4) {
        #pragma unroll
        for (int e = 0; e < 4; ++e) {
            float dv = ca * acc[e];
            float dg = ((row0 + e) == col) ? 1.0f : 0.0f;
            D[(row0 + e) * STRU + col]  = packhl(dv);
            DT[(row0 + e) * STRU + col] = packhl(dv + dg);
        }
    } else if constexpr (MODE == 5) {
        #pragma unroll
        for (int e = 0; e < 4; ++e) {
            float t  = unpackf(R[(row0 + e) * STRU + col]);
            float dg = ((row0 + e) == col) ? 1.0f : 0.0f;
            float base = ca * t - dg;
            float sv   = cb * acc[e];
            D[(row0 + e) * STRU + col]  = packhl(base + sv);
            DT[(row0 + e) * STRU + col] = packhl(base - sv);
        }
    }
}

// Krylov doubling: Xt rows [k,2k) <- (rows j<k of Xt) * M^T.
// Garbage in source rows >= k only feeds discarded output rows (MFMA row m of D
// depends only on row m of A-operand). Unit = (row tile, col block); waves 0..4*nt-1.
__device__ __forceinline__ void dbl64(unsigned* Xt, const unsigned* M, int k, int tid) {
    const int lane = tid & 63, w = tid >> 6;
    const int nh = lane & 15, qh = lane >> 4;
    const int nt = (k + 15) >> 4;
    if (w < 4 * nt) {
        const int t = w >> 2, cb = w & 3;
        v4f acc = {0, 0, 0, 0};
        #pragma unroll
        for (int kk = 0; kk < 2; ++kk) {
            const int kc = kk * 32 + qh * 8;
            v8s ph, pl, mh, ml;
            load_frag(Xt + (t * 16 + nh) * STRU + kc, ph, pl);
            load_frag(M + (cb * 16 + nh) * STRU + kc, mh, ml);
            acc = MFMA(ph, mh, acc, 0, 0, 0);
            acc = MFMA(ph, ml, acc, 0, 0, 0);
            acc = MFMA(pl, mh, acc, 0, 0, 0);
        }
        #pragma unroll
        for (int e = 0; e < 4; ++e) {
            const int j = t * 16 + qh * 4 + e;
            if (j < k) Xt[(k + j) * STRU + cb * 16 + nh] = packhl(acc[e]);
        }
    }
}

__launch_bounds__(1024)
__global__ void krylov_kernel(const float* __restrict__ A,
                              const float* __restrict__ Bv,
                              const float* __restrict__ Cv,
                              const float* __restrict__ logdt,
                              float* __restrict__ out)
{
    const int h    = blockIdx.x;
    const int tid  = threadIdx.x;
    const int lane = tid & 63;
    const int w    = tid >> 6;

    __shared__ __align__(16) unsigned SM[6][64 * STRU];
    __shared__ float Bl[64];

    const float dt = expf(logdt[h]);
    const float c  = 0.5f * dt;
    const float al = 1.0f + 0.5f * c;
    const float sd = -(c * c) / (al * al);   // D~ = sd * (S S^T)
    const float c1 = 2.0f / al;              // X = c1*T + c2*SH - I
    const float c2 = 2.0f * c / (al * al);

    const float* Ah = A + (size_t)h * 4096;

    // ---- P0: pack S = A + 0.5I into SM0; B -> Bl; Ut row0 = C -> SM5 ----
    {
        const int r = tid >> 4, c0 = (tid & 15) * 4;
        float4 v = *(const float4*)(Ah + tid * 4);
        if (r == c0 + 0) v.x += 0.5f;
        if (r == c0 + 1) v.y += 0.5f;
        if (r == c0 + 2) v.z += 0.5f;
        if (r == c0 + 3) v.w += 0.5f;
        uint4 pk = make_uint4(packhl(v.x), packhl(v.y), packhl(v.z), packhl(v.w));
        *(uint4*)&SM[0][r * STRU + c0] = pk;
    }
    if (tid < 64) Bl[tid] = Bv[h * 64 + tid];
    else if (tid < 128) SM[5][tid - 64] = packhl(Cv[h * 64 + (tid - 64)]);
    __syncthreads();

    // ---- M1: S*S^T -> D~ = sd*acc (SM1), T0 = D~ + I (SM2) ----
    mm64<4>(SM[0], SM[0], SM[1], SM[2], nullptr, nullptr, sd, 0.f, tid);
    __syncthreads();
    // ---- Horner (T_i all symmetric): T1, T2, T3 = T ----
    mm64<1>(SM[1], SM[2], SM[3], nullptr, nullptr, nullptr, 0.f, 0.f, tid);
    __syncthreads();
    mm64<1>(SM[1], SM[3], SM[2], nullptr, nullptr, nullptr, 0.f, 0.f, tid);
    __syncthreads();
    mm64<1>(SM[1], SM[2], SM[3], nullptr, nullptr, nullptr, 0.f, 0.f, tid);
    __syncthreads();
    // ---- M5: SH = S*T; X = c1*T + c2*SH - I (SM2), XT = c1*T - c2*SH - I (SM1) ----
    mm64<5>(SM[0], SM[3], SM[2], SM[1], nullptr, SM[3], c1, c2, tid);
    __syncthreads();

    // ---- seed: Vt row0 = dB = (dt/2)(X*B + B) ----
    if (w == 0) {
        const unsigned* Xr = SM[2] + lane * STRU;
        float acc = 0.0f;
        #pragma unroll
        for (int m4 = 0; m4 < 16; ++m4) {
            uint4 xv = *(const uint4*)(Xr + 4 * m4);
            float4 b4 = *(const float4*)&Bl[4 * m4];
            acc += unpackf(xv.x) * b4.x + unpackf(xv.y) * b4.y
                 + unpackf(xv.z) * b4.z + unpackf(xv.w) * b4.w;
        }
        SM[4][lane] = packhl(c * (acc + Bl[lane]));
    }
    __syncthreads();

    // ---- ladder A: s=0..5: dual-square X -> X^2, X^2T; double Vt with X ----
    unsigned *bX = SM[2], *bXT = SM[1], *bN = SM[0], *bNT = SM[3];
    #pragma unroll 1
    for (int s = 0; s < 6; ++s) {
        mm64<3>(bX, bXT, bN, bNT, nullptr, nullptr, 0.f, 0.f, tid);
        dbl64(SM[4], bX, 1 << s, tid);
        __syncthreads();
        unsigned* t0 = bX;  bX  = bN;  bN  = t0;
        t0 = bXT; bXT = bNT; bNT = t0;
    }
    // bX = E = dA^64, bXT = E^T

    // ---- ladder B: s=0..5: double Ut with XT = (E^T)^(2^s); dual-square (s<5) ----
    #pragma unroll 1
    for (int s = 0; s < 6; ++s) {
        if (s < 5) mm64<3>(bX, bXT, bN, bNT, nullptr, nullptr, 0.f, 0.f, tid);
        dbl64(SM[5], bXT, 1 << s, tid);
        __syncthreads();
        if (s < 5) {
            unsigned* t0 = bX;  bX  = bN;  bN  = t0;
            t0 = bXT; bXT = bNT; bNT = t0;
        }
    }

    // ---- final: out[h][64q + r] = sum_n Ut[q][n] * Vt[r][n] ----
    mm64<2>(SM[5], SM[4], nullptr, nullptr, out + (size_t)h * 4096, nullptr,
            0.f, 0.f, tid);
}

extern "C" void kernel_launch(void* const* d_in, const int* in_sizes, int n_in,
                              void* d_out, int out_size, void* d_ws, size_t ws_size,
                              hipStream_t stream) {
    const float* A  = (const float*)d_in[0];
    const float* B  = (const float*)d_in[1];
    const float* C  = (const float*)d_in[2];
    const float* ld = (const float*)d_in[3];
    float* out = (float*)d_out;
    const int H = in_sizes[3];   // 256 heads
    krylov_kernel<<<H, 1024, 0, stream>>>(A, B, C, ld, out);
}